// Round 2
// baseline (242.696 us; speedup 1.0000x reference)
//
#include <hip/hip_runtime.h>

// bMomentumLIF forward: x[B,T,F] fp32 -> spikes[B,T,F] fp32
// Recurrence per neuron (b,f) over t:
//   u  = u_last * 0.5 + x[t]            (TAU=2, /2 == *0.5 exactly)
//   s  = (u - th >= 0) ? 1 : 0
//   m  = mt*m + (1-mt)*(u - u_last)
//   u' = (u*lb + m*(1-lb)) * (1-s)
// Memory-bound: 128 MiB in + 128 MiB out -> ~43 us floor @ 6.3 TB/s.
//
// R1 (float4/thread, full unroll): 236 us, 1.14 TB/s -> latency-bound.
// R2: float2/thread (16 waves/CU) + explicit prefetch ring depth 4.

constexpr int B  = 64;
constexpr int T  = 64;
constexpr int F  = 8192;
constexpr int F2 = F / 2;   // float2 granularity along F
constexpr int P  = 4;       // prefetch depth (ring buffer)

__global__ __launch_bounds__(256) void lif_fwd_kernel(
    const float2* __restrict__ x,
    const float*  __restrict__ momentum,
    const float*  __restrict__ lamb,
    const float*  __restrict__ thresholds,
    float2*       __restrict__ out)
{
    // No FMA contraction: spike threshold is an exact compare vs the numpy
    // fp32 reference; contraction changes rounding of the m-update and can
    // flip spikes at the boundary. R1 confirmed bit-exact with this order.
#pragma clang fp contract(off)

    const int tid = blockIdx.x * blockDim.x + threadIdx.x;   // 0 .. B*F2-1
    const int b   = tid / F2;
    const int f2  = tid - b * F2;

    const float mt  = momentum[0];
    const float omt = 1.0f - mt;
    const float lb  = lamb[0];
    const float olb = 1.0f - lb;
    const float th  = thresholds[0];

    const int base = b * (T * F2) + f2;   // float2 index; stride F2 per step

    // Prime the prefetch ring: P loads in flight before any compute.
    float2 buf[P];
#pragma unroll
    for (int i = 0; i < P; ++i) buf[i] = x[base + i * F2];

    float u0 = 0.0f, u1 = 0.0f;
    float m0 = 0.0f, m1 = 0.0f;

    int load_idx  = base + P * F2;
    int store_idx = base;

#pragma unroll 4
    for (int t = 0; t < T; ++t) {
        const float2 xi = buf[t & (P - 1)];

        // Issue the t+P load immediately so it overlaps this iteration's
        // dependent compute chain (wave-uniform guard, cheap).
        if (t + P < T) {
            buf[t & (P - 1)] = x[load_idx];
            load_idx += F2;
        }

        float2 sv;
        // component 0
        {
            const float u  = u0 * 0.5f + xi.x;
            const float s  = ((u - th) >= 0.0f) ? 1.0f : 0.0f;
            const float a  = mt * m0;
            const float bq = omt * (u - u0);
            m0 = a + bq;
            u0 = (u * lb + m0 * olb) * (1.0f - s);
            sv.x = s;
        }
        // component 1
        {
            const float u  = u1 * 0.5f + xi.y;
            const float s  = ((u - th) >= 0.0f) ? 1.0f : 0.0f;
            const float a  = mt * m1;
            const float bq = omt * (u - u1);
            m1 = a + bq;
            u1 = (u * lb + m1 * olb) * (1.0f - s);
            sv.y = s;
        }

        out[store_idx] = sv;
        store_idx += F2;
    }
}

extern "C" void kernel_launch(void* const* d_in, const int* in_sizes, int n_in,
                              void* d_out, int out_size, void* d_ws, size_t ws_size,
                              hipStream_t stream) {
    const float2* x   = (const float2*)d_in[0];
    const float*  mom = (const float*)d_in[1];
    const float*  lmb = (const float*)d_in[2];
    const float*  thr = (const float*)d_in[3];
    float2* out = (float2*)d_out;

    const int n_threads = B * F2;          // 262144
    const int block = 256;
    const int grid = n_threads / block;    // 1024
    lif_fwd_kernel<<<grid, block, 0, stream>>>(x, mom, lmb, thr, out);
}

// Round 4
// 240.045 us; speedup vs baseline: 1.0110x; 1.0110x over previous
//
#include <hip/hip_runtime.h>

// bMomentumLIF forward: x[B,T,F] fp32 -> spikes[B,T,F] fp32
// Recurrence per neuron (b,f) over t:
//   u  = u_last * 0.5 + x[t]            (TAU=2, /2 == *0.5 exactly)
//   s  = (u - th >= 0) ? 1 : 0
//   m  = mt*m + (1-mt)*(u - u_last)
//   u' = (u*lb + m*(1-lb)) * (1-s)
//
// R1 float4/full-unroll: bench 236 (kernel <80us, unprofiled).
// R2 float2/ring4: kernel 80.2us @ 2.5 TB/s — vmcnt in-order retirement:
//    waiting for load L_t also waits store S_{t-5} (4 iters of slack only).
// R3: ring depth 8 + nontemporal store — compile error (HIP_vector_type not
//    accepted by the builtin). R4: same, with ext_vector_type for the store.

constexpr int B  = 64;
constexpr int T  = 64;
constexpr int F  = 8192;
constexpr int F2 = F / 2;   // float2 granularity along F
constexpr int P  = 8;       // prefetch ring depth

typedef float v2f __attribute__((ext_vector_type(2)));  // native clang vector

__global__ __launch_bounds__(256) void lif_fwd_kernel(
    const float2* __restrict__ x,
    const float*  __restrict__ momentum,
    const float*  __restrict__ lamb,
    const float*  __restrict__ thresholds,
    v2f*          __restrict__ out)
{
    // No FMA contraction: spike threshold is an exact compare vs the numpy
    // fp32 reference; contraction changes rounding of the m-update and can
    // flip spikes at the boundary. R1/R2 confirmed bit-exact with this order.
#pragma clang fp contract(off)

    const int tid = blockIdx.x * blockDim.x + threadIdx.x;   // 0 .. B*F2-1
    const int b   = tid / F2;
    const int f2  = tid - b * F2;

    const float mt  = momentum[0];
    const float omt = 1.0f - mt;
    const float lb  = lamb[0];
    const float olb = 1.0f - lb;
    const float th  = thresholds[0];

    const int base = b * (T * F2) + f2;   // float2 index; stride F2 per step

    // Prime the prefetch ring: P loads in flight before any compute.
    float2 buf[P];
#pragma unroll
    for (int i = 0; i < P; ++i) buf[i] = x[base + i * F2];

    float u0 = 0.0f, u1 = 0.0f;
    float m0 = 0.0f, m1 = 0.0f;

    int load_idx  = base + P * F2;
    int store_idx = base;

#pragma unroll 8
    for (int t = 0; t < T; ++t) {
        const float2 xi = buf[t & (P - 1)];

        // Refill this ring slot with the t+P element; by the time we wait on
        // it, stores from iteration t (issued below) have had P iterations
        // to retire, so the in-order vmcnt wait is load-limited, not
        // store-limited.
        if (t + P < T) {
            buf[t & (P - 1)] = x[load_idx];
            load_idx += F2;
        }

        v2f sv;
        // component 0
        {
            const float u  = u0 * 0.5f + xi.x;
            const float s  = ((u - th) >= 0.0f) ? 1.0f : 0.0f;
            const float a  = mt * m0;
            const float bq = omt * (u - u0);
            m0 = a + bq;
            u0 = (u * lb + m0 * olb) * (1.0f - s);
            sv.x = s;
        }
        // component 1
        {
            const float u  = u1 * 0.5f + xi.y;
            const float s  = ((u - th) >= 0.0f) ? 1.0f : 0.0f;
            const float a  = mt * m1;
            const float bq = omt * (u - u1);
            m1 = a + bq;
            u1 = (u * lb + m1 * olb) * (1.0f - s);
            sv.y = s;
        }

        // Write-once output: nontemporal store, don't pollute L2/L3.
        __builtin_nontemporal_store(sv, &out[store_idx]);
        store_idx += F2;
    }
}

extern "C" void kernel_launch(void* const* d_in, const int* in_sizes, int n_in,
                              void* d_out, int out_size, void* d_ws, size_t ws_size,
                              hipStream_t stream) {
    const float2* x   = (const float2*)d_in[0];
    const float*  mom = (const float*)d_in[1];
    const float*  lmb = (const float*)d_in[2];
    const float*  thr = (const float*)d_in[3];
    v2f* out = (v2f*)d_out;

    const int n_threads = B * F2;          // 262144
    const int block = 256;
    const int grid = n_threads / block;    // 1024
    lif_fwd_kernel<<<grid, block, 0, stream>>>(x, mom, lmb, thr, out);
}